// Round 4
// baseline (69.207 us; speedup 1.0000x reference)
//
#include <hip/hip_runtime.h>
#include <hip/hip_bf16.h>

// y = (x * (255/q[c]) + noise) * (q[c]/255)
// x, noise, y: (N=32, C=64, H=128, W=128) fp32 contiguous. q: 64 fp32.
// channel of float4 index i4: (i4 >> 12) & 63.
//
// Persistent grid: 2048 blocks x 256 thr = 524288 threads; n4 = 2^23 ->
// exactly 16 iterations/thread, stride = 2^19 float4s = 128 channels == 0
// mod 64  =>  each thread's channel is INVARIANT: hoist q/r/s out of loop.
// Depth-4 software pipeline: prefetch iter j+4 while processing iter j.
// All pipeline-buffer indices are compile-time (no scratch spill).

typedef float vfloat4 __attribute__((ext_vector_type(4)));

__global__ __launch_bounds__(256) void redmarkjpeg_pipe(
    const vfloat4* __restrict__ x,
    const float*   __restrict__ q,
    const vfloat4* __restrict__ noise,
    vfloat4* __restrict__ out,
    int iters, int stride)
{
    constexpr int D = 4;
    const int tid = blockIdx.x * blockDim.x + threadIdx.x;

    // Thread-invariant channel scale factors.
    const int   c  = (tid >> 12) & 63;
    const float qv = q[c];
    const float r  = 255.0f / qv;
    const float s  = qv / 255.0f;

    vfloat4 xb[D], nb[D];
    // Prologue: fill the pipeline (8 loads in flight).
    #pragma unroll
    for (int d = 0; d < D; ++d) {
        xb[d] = x[tid + d * stride];
        nb[d] = noise[tid + d * stride];
    }

    int j = 0;
    for (; j + D < iters; j += D) {
        #pragma unroll
        for (int d = 0; d < D; ++d) {
            const int ii = tid + (j + d) * stride;
            vfloat4 o;
            o.x = (xb[d].x * r + nb[d].x) * s;
            o.y = (xb[d].y * r + nb[d].y) * s;
            o.z = (xb[d].z * r + nb[d].z) * s;
            o.w = (xb[d].w * r + nb[d].w) * s;
            // Prefetch next group's slot d before the store.
            xb[d] = x[ii + D * stride];
            nb[d] = noise[ii + D * stride];
            __builtin_nontemporal_store(o, &out[ii]);
        }
    }
    // Epilogue: drain the last D iterations (no prefetch).
    #pragma unroll
    for (int d = 0; d < D; ++d) {
        const int ii = tid + (j + d) * stride;
        vfloat4 o;
        o.x = (xb[d].x * r + nb[d].x) * s;
        o.y = (xb[d].y * r + nb[d].y) * s;
        o.z = (xb[d].z * r + nb[d].z) * s;
        o.w = (xb[d].w * r + nb[d].w) * s;
        __builtin_nontemporal_store(o, &out[ii]);
    }
}

// Fallback (round-3 style) in case sizes ever change.
__global__ __launch_bounds__(256) void redmarkjpeg_simple(
    const vfloat4* __restrict__ x,
    const float*   __restrict__ q,
    const vfloat4* __restrict__ noise,
    vfloat4* __restrict__ out,
    int n4)
{
    int i = blockIdx.x * blockDim.x + threadIdx.x;
    const int stride = gridDim.x * blockDim.x;
    for (; i < n4; i += stride) {
        const int c = (i >> 12) & 63;
        const float qv = q[c];
        const float r  = 255.0f / qv;
        const float s  = qv / 255.0f;
        const vfloat4 xv = x[i];
        const vfloat4 nv = noise[i];
        vfloat4 o;
        o.x = (xv.x * r + nv.x) * s;
        o.y = (xv.y * r + nv.y) * s;
        o.z = (xv.z * r + nv.z) * s;
        o.w = (xv.w * r + nv.w) * s;
        __builtin_nontemporal_store(o, &out[i]);
    }
}

extern "C" void kernel_launch(void* const* d_in, const int* in_sizes, int n_in,
                              void* d_out, int out_size, void* d_ws, size_t ws_size,
                              hipStream_t stream)
{
    const vfloat4* x     = (const vfloat4*)d_in[0];
    const float*   q     = (const float*)d_in[1];
    const vfloat4* noise = (const vfloat4*)d_in[2];
    vfloat4*       out   = (vfloat4*)d_out;

    const int n4    = out_size / 4;          // 8,388,608 = 2^23
    const int block = 256;
    const int grid  = 2048;                  // 8192 waves = 32/CU, fully resident
    const int stride = grid * block;         // 524,288
    const int iters  = n4 / stride;          // 16

    // Pipelined kernel requires: exact division, iters > D(=4), and
    // stride a multiple of 64 channels (guaranteed: stride % (64*4096) == 0).
    if (n4 % stride == 0 && iters > 4 && (stride % (64 * 4096)) == 0) {
        redmarkjpeg_pipe<<<grid, block, 0, stream>>>(x, q, noise, out, iters, stride);
    } else {
        redmarkjpeg_simple<<<grid, block, 0, stream>>>(x, q, noise, out, n4);
    }
}

// Round 5
// 64.189 us; speedup vs baseline: 1.0782x; 1.0782x over previous
//
#include <hip/hip_runtime.h>
#include <hip/hip_bf16.h>

// y = (x * (255/q[c]) + noise) * (q[c]/255)
// x, noise, y: (N=32, C=64, H=128, W=128) fp32 contiguous. q: 64 fp32.
// channel of float4 index i4: (i4 >> 12) & 63.
//
// Round-3 structure (fastest so far: 62.5 us): 8192 blocks, U=4, all 8 loads
// issued up front, nt stores. NEW: selective non-temporal LOADS on the last
// 1/8 of both inputs. Inputs total 268 MB vs 256 MiB L3 -- 12 MB over.
// Excluding 33.6 MB from allocation leaves a ~235 MB resident set that fits,
// so steady-state HBM fetch should drop from 134 MB to ~34 MB.
// The nt/normal branch is wave-uniform (idx is uniform across the wave mod
// lane offset; cutoff is far from any wave boundary effect at 4-elem grain).

typedef float vfloat4 __attribute__((ext_vector_type(4)));

__global__ __launch_bounds__(256) void redmarkjpeg_kernel(
    const vfloat4* __restrict__ x,
    const float*   __restrict__ q,
    const vfloat4* __restrict__ noise,
    vfloat4* __restrict__ out,
    int n4, int nt_cut)
{
    constexpr int U = 4;
    const int tid    = blockIdx.x * blockDim.x + threadIdx.x;
    const int stride = gridDim.x * blockDim.x;

    int     idx[U];
    vfloat4 xv[U], nv[U];
    bool    ok[U];

    #pragma unroll
    for (int k = 0; k < U; ++k) {
        idx[k] = tid + k * stride;
        ok[k]  = idx[k] < n4;
    }
    // Issue all loads first (8 in flight per thread).
    #pragma unroll
    for (int k = 0; k < U; ++k) {
        if (ok[k]) {
            if (idx[k] >= nt_cut) {
                xv[k] = __builtin_nontemporal_load(&x[idx[k]]);
                nv[k] = __builtin_nontemporal_load(&noise[idx[k]]);
            } else {
                xv[k] = x[idx[k]];
                nv[k] = noise[idx[k]];
            }
        }
    }
    #pragma unroll
    for (int k = 0; k < U; ++k) {
        if (ok[k]) {
            const int c = (idx[k] >> 12) & 63;
            const float qv = q[c];
            const float r  = 255.0f / qv;
            const float s  = qv / 255.0f;
            vfloat4 o;
            o.x = (xv[k].x * r + nv[k].x) * s;
            o.y = (xv[k].y * r + nv[k].y) * s;
            o.z = (xv[k].z * r + nv[k].z) * s;
            o.w = (xv[k].w * r + nv[k].w) * s;
            __builtin_nontemporal_store(o, &out[idx[k]]);
        }
    }
}

extern "C" void kernel_launch(void* const* d_in, const int* in_sizes, int n_in,
                              void* d_out, int out_size, void* d_ws, size_t ws_size,
                              hipStream_t stream)
{
    const vfloat4* x     = (const vfloat4*)d_in[0];
    const float*   q     = (const float*)d_in[1];
    const vfloat4* noise = (const vfloat4*)d_in[2];
    vfloat4*       out   = (vfloat4*)d_out;

    const int n4 = out_size / 4;                 // 8,388,608
    const int block = 256;
    constexpr int U = 4;
    const int grid = (n4 + block * U - 1) / (block * U);  // 8192 blocks

    // Last 1/8 of each input is loaded non-temporally: allocating set =
    // 2 * (7/8) * 134 MB = 235 MB < 256 MiB L3.
    const int nt_cut = n4 - n4 / 8;

    redmarkjpeg_kernel<<<grid, block, 0, stream>>>(x, q, noise, out, n4, nt_cut);
}

// Round 6
// 62.691 us; speedup vs baseline: 1.1039x; 1.0239x over previous
//
#include <hip/hip_runtime.h>
#include <hip/hip_bf16.h>

// y = (x * (255/q[c]) + noise) * (q[c]/255)
// x, noise, y: (N=32, C=64, H=128, W=128) fp32, contiguous. q: 64 fp32.
// channel of float4 index i4: (i4 >> 12) & 63  (HW=16384 elems = 4096 float4s).
//
// Memory-bound. Inputs = 268 MB, output = 134 MB, L3 = 256 MiB.
// Best structure found (62.5 us): 8192 one-shot blocks, U=4, all 8 loads
// issued up front, non-temporal stores (output never pollutes L3).
// Steady state: FETCH 134 MB (L3 serves ~50% of input reads), WRITE 134 MB;
// aggregate CU traffic 402 MB / 62.5 us = 6.4 TB/s = copy ceiling.
// R4 (persistent+pipelined) and R5 (selective nt loads) both regressed.

typedef float vfloat4 __attribute__((ext_vector_type(4)));

__global__ __launch_bounds__(256) void redmarkjpeg_kernel(
    const vfloat4* __restrict__ x,
    const float*   __restrict__ q,
    const vfloat4* __restrict__ noise,
    vfloat4* __restrict__ out,
    int n4)
{
    constexpr int U = 4;
    const int tid    = blockIdx.x * blockDim.x + threadIdx.x;
    const int stride = gridDim.x * blockDim.x;

    int     idx[U];
    vfloat4 xv[U], nv[U];
    bool    ok[U];

    #pragma unroll
    for (int k = 0; k < U; ++k) {
        idx[k] = tid + k * stride;
        ok[k]  = idx[k] < n4;
    }
    // Issue all loads first (independent -> 8 loads in flight per thread).
    #pragma unroll
    for (int k = 0; k < U; ++k) {
        if (ok[k]) { xv[k] = x[idx[k]]; nv[k] = noise[idx[k]]; }
    }
    #pragma unroll
    for (int k = 0; k < U; ++k) {
        if (ok[k]) {
            const int c = (idx[k] >> 12) & 63;
            const float qv = q[c];
            const float r  = 255.0f / qv;
            const float s  = qv / 255.0f;
            vfloat4 o;
            o.x = (xv[k].x * r + nv[k].x) * s;
            o.y = (xv[k].y * r + nv[k].y) * s;
            o.z = (xv[k].z * r + nv[k].z) * s;
            o.w = (xv[k].w * r + nv[k].w) * s;
            __builtin_nontemporal_store(o, &out[idx[k]]);
        }
    }
}

extern "C" void kernel_launch(void* const* d_in, const int* in_sizes, int n_in,
                              void* d_out, int out_size, void* d_ws, size_t ws_size,
                              hipStream_t stream)
{
    const vfloat4* x     = (const vfloat4*)d_in[0];
    const float*   q     = (const float*)d_in[1];
    const vfloat4* noise = (const vfloat4*)d_in[2];
    vfloat4*       out   = (vfloat4*)d_out;

    const int n4 = out_size / 4;                 // 8,388,608
    const int block = 256;
    constexpr int U = 4;
    const int grid = (n4 + block * U - 1) / (block * U);  // 8192 blocks
    redmarkjpeg_kernel<<<grid, block, 0, stream>>>(x, q, noise, out, n4);
}